// Round 9
// baseline (6737.186 us; speedup 1.0000x reference)
//
#include <hip/hip_runtime.h>
#include <hip/hip_bf16.h>

// MPNN GNN: V=12500 (feat 32), E=200000 (feat 16), H=32, 6 steps.
// msg[e,o] = sum_k a[e,k]*T[src[e],k,o] + Tb[src[e],o],  a loop-invariant.
// R9: edge pass = MFMA 16x16x32 bf16, split-precision 3-GEMM:
//   msg ~= Ahi@Thi + Alo@Thi + Ahi@Tlo   (error ~2^-16, f32 accum)
// a streamed f32, split to bf16 in regs. T computed f32 (VALU) and written to
// LDS directly in B-fragment layout (hi/lo). CSR padded to 16/node; pad rows
// skipped at flush (one atomic per real (e,o)).

#define NB 4  // src nodes per k_step block

typedef __attribute__((ext_vector_type(8))) short bf16x8;
typedef __attribute__((ext_vector_type(4))) float f32x4;

// ---------------- node projection: h = relu(nf@w1+b1)@w2+b2 ----------------
__global__ __launch_bounds__(256) void k_proj(
    const float* __restrict__ nf, const float* __restrict__ w1,
    const float* __restrict__ b1, const float* __restrict__ w2,
    const float* __restrict__ b2, float* __restrict__ hseq, int nV) {
  __shared__ float sw1[1024], sw2[1024], sb1[32], sb2[32];
  __shared__ float sx[8][32], st1[8][32];
  int t = threadIdx.x;
  int v0 = blockIdx.x * 8;
  for (int i = t; i < 1024; i += 256) { sw1[i] = w1[i]; sw2[i] = w2[i]; }
  if (t < 32) { sb1[t] = b1[t]; sb2[t] = b2[t]; }
  {
    int g = v0 * 32 + t;
    sx[t >> 5][t & 31] = (g < nV * 32) ? nf[g] : 0.f;
  }
  __syncthreads();
  int n = t >> 5, j = t & 31;
  float s = sb1[j];
#pragma unroll
  for (int i = 0; i < 32; i++) s += sx[n][i] * sw1[i * 32 + j];
  st1[n][j] = fmaxf(s, 0.f);
  __syncthreads();
  float h = sb2[j];
#pragma unroll
  for (int i = 0; i < 32; i++) h += st1[n][i] * sw2[i * 32 + j];
  if (v0 + n < nV) hseq[(size_t)(v0 + n) * 32 + j] = h;
}

// ---------------- w2 transpose: w2t[(k*32+c)*32+i] = w2[k*1024+i*32+c] -----
__global__ __launch_bounds__(256) void k_w2t(const float* __restrict__ w2,
                                             float* __restrict__ w2t) {
  int id = blockIdx.x * 256 + threadIdx.x;  // 131072 total
  int k = id >> 10, rest = id & 1023, i = rest >> 5, c = rest & 31;
  w2t[((k * 32 + c) << 5) + i] = w2[id];
}

// ---------------- CSR by src, padded to multiples of 16 --------------------
__global__ __launch_bounds__(256) void k_count(const int* __restrict__ key,
                                               int* __restrict__ counts, int nE) {
  int e = blockIdx.x * 256 + threadIdx.x;
  if (e < nE) atomicAdd(&counts[key[e]], 1);
}

__global__ __launch_bounds__(1024) void k_scan(const int* __restrict__ counts,
                                               int* __restrict__ row_ptr, int nV) {
  __shared__ int buf[1024];
  __shared__ int s_off;
  int t = threadIdx.x;
  if (t == 0) s_off = 0;
  __syncthreads();
  for (int base = 0; base < nV; base += 1024) {
    int x = (base + t < nV) ? ((counts[base + t] + 15) & ~15) : 0;  // pad to 16
    buf[t] = x;
    __syncthreads();
    for (int d = 1; d < 1024; d <<= 1) {
      int v2 = (t >= d) ? buf[t - d] : 0;
      __syncthreads();
      buf[t] += v2;
      __syncthreads();
    }
    int incl = buf[t];
    int off = s_off;
    __syncthreads();
    if (base + t < nV) row_ptr[base + t] = off + incl - x;  // exclusive
    if (t == 1023) s_off = off + incl;
    __syncthreads();
  }
  if (t == 0) row_ptr[nV] = s_off;
}

__global__ __launch_bounds__(256) void k_copy(const int* __restrict__ row_ptr,
                                              int* __restrict__ cursor, int nV) {
  int v = blockIdx.x * 256 + threadIdx.x;
  if (v < nV) cursor[v] = row_ptr[v];
}

// scatter: perm[p]=edge id, dstp[p]=dst (dstp pre-memset to -1 for pads)
__global__ __launch_bounds__(256) void k_scatter(const int* __restrict__ key,
                                                 const int* __restrict__ dst,
                                                 int* __restrict__ cursor,
                                                 int* __restrict__ perm,
                                                 int* __restrict__ dstp, int nE) {
  int e = blockIdx.x * 256 + threadIdx.x;
  if (e < nE) {
    int p = atomicAdd(&cursor[key[e]], 1);
    perm[p] = e;
    dstp[p] = dst[e];
  }
}

// ---------------- edge MLP (permuted order): aq[idx][128] f32, pads 0 ------
__global__ __launch_bounds__(256) void k_edgebuild(
    const float* __restrict__ ef, const float* __restrict__ w1,
    const float* __restrict__ b1, const int* __restrict__ perm,
    const int* __restrict__ dstp, const int* __restrict__ rp16,
    float* __restrict__ aq, int nV) {
  __shared__ float sw1[16 * 128], sb1[128], sef[2 * 16];
  __shared__ int spad[2];
  int t = threadIdx.x;
  int total = rp16[nV];
  int i0 = blockIdx.x * 2;
  if (i0 >= total) return;
  for (int i = t; i < 2048; i += 256) sw1[i] = w1[i];
  if (t < 128) sb1[t] = b1[t];
  if (t < 32) {
    int ii = i0 + (t >> 4);
    bool pad = (ii >= total) || (dstp[ii] < 0);
    if ((t & 15) == 0) spad[t >> 4] = pad ? 1 : 0;
    sef[t] = pad ? 0.f : ef[(size_t)perm[ii] * 16 + (t & 15)];
  }
  __syncthreads();
  int el = t >> 7, c = t & 127;
  int ii = i0 + el;
  if (ii >= total) return;
  float s = sb1[c];
#pragma unroll
  for (int i = 0; i < 16; i++) s += sef[el * 16 + i] * sw1[i * 128 + c];
  aq[(size_t)ii * 128 + c] = spad[el] ? 0.f : fmaxf(s, 0.f);
}

// ---------------- per-step: VALU T (f32->split bf16 frag LDS) + MFMA edges -
// LDS sTB ushort[(((n*4+kc)*2+h)*2+sp)*512 + l*8 + j]  (64 KB)
//   holds T[n][kc*32 + (l>>4)*8 + j][(l&15) + 16*h], sp: 0=hi 1=lo
__global__ __launch_bounds__(256) void k_step(
    const float* __restrict__ hseq, const float* __restrict__ w2t,
    const float* __restrict__ b2, const float* __restrict__ aq,
    const int* __restrict__ rp16, const int* __restrict__ dstp,
    float* __restrict__ agg, int nV) {
  __shared__ unsigned short sTB[32768];
  __shared__ float sh[NB][32];
  __shared__ float sTb[NB][32];
  __shared__ int s_rp[NB + 1];
  int t = threadIdx.x;
  int v0 = blockIdx.x * NB;
  if (t <= NB) {
    int v = v0 + t;
    if (v > nV) v = nV;
    s_rp[t] = rp16[v];
  }
  if (t < NB * 32) {
    int n = t >> 5, v = v0 + n;
    sh[n][t & 31] = (v < nV) ? hseq[(size_t)v * 32 + (t & 31)] : 0.f;
  }
  __syncthreads();
  int beg = s_rp[0], end = s_rp[NB];
  if (beg == end) return;  // block-uniform

  if (t < NB * 32) {  // Tb[n][o] = sum_i h[n][i]*e_b2[i*32+o] (b2 via w2t? no: raw)
    int n = t >> 5, o = t & 31;
    float s = 0.f;
#pragma unroll
    for (int i = 0; i < 32; i++) s += sh[n][i] * b2[i * 32 + o];
    sTb[n][o] = s;
  }

  // ---- T-phase: 2 frag-slots per thread; slot = (kc,h,l) ----
  for (int s = t; s < 512; s += 256) {
    int kc = s >> 7, h = (s >> 6) & 1, l = s & 63;
    int c = (l & 15) + h * 16;
    int kbase = kc * 32 + ((l >> 4) << 3);
    float acc[NB][8];
#pragma unroll
    for (int n = 0; n < NB; n++)
#pragma unroll
      for (int j = 0; j < 8; j++) acc[n][j] = 0.f;
#pragma unroll
    for (int j = 0; j < 8; j++) {
      const float4* wp = (const float4*)(w2t + ((size_t)((kbase + j) * 32 + c) << 5));
#pragma unroll
      for (int iq = 0; iq < 8; iq++) {
        float4 w4 = wp[iq];
        int i0 = iq * 4;
#pragma unroll
        for (int n = 0; n < NB; n++) {
          acc[n][j] += sh[n][i0] * w4.x + sh[n][i0 + 1] * w4.y +
                       sh[n][i0 + 2] * w4.z + sh[n][i0 + 3] * w4.w;
        }
      }
    }
#pragma unroll
    for (int n = 0; n < NB; n++) {
      unsigned int hi[4], lo[4];
#pragma unroll
      for (int jp = 0; jp < 4; jp++) {
        float a0 = acc[n][2 * jp], a1 = acc[n][2 * jp + 1];
        unsigned u0 = __float_as_uint(a0), u1 = __float_as_uint(a1);
        unsigned h0 = u0 >> 16, h1 = u1 >> 16;
        float f0 = __uint_as_float(h0 << 16), f1 = __uint_as_float(h1 << 16);
        unsigned l0 = __float_as_uint(a0 - f0) >> 16;
        unsigned l1 = __float_as_uint(a1 - f1) >> 16;
        hi[jp] = h0 | (h1 << 16);
        lo[jp] = l0 | (l1 << 16);
      }
      int ub = ((((n * 4 + kc) * 2 + h) * 2 + 0) * 64 + l) * 8;
      *(uint4*)&sTB[ub] = make_uint4(hi[0], hi[1], hi[2], hi[3]);
      *(uint4*)&sTB[ub + 512] = make_uint4(lo[0], lo[1], lo[2], lo[3]);
    }
  }
  __syncthreads();

  // ---- edge MFMA phase: wave per 16-edge tile ----
  int wid = t >> 6, l = t & 63;
  int r = l & 15;            // A row within tile
  int kg = (l >> 4) << 3;    // k sub-offset
  int n = 0;
  for (int idx16 = beg + wid * 16; idx16 < end; idx16 += 64) {
    while (idx16 >= s_rp[n + 1]) n++;
    // A-frags: f32 load + reg split to bf16 hi/lo
    bf16x8 Ahi[4], Alo[4];
    const float* arow = aq + (size_t)(idx16 + r) * 128 + kg;
#pragma unroll
    for (int kc = 0; kc < 4; kc++) {
      float4 x = *(const float4*)(arow + kc * 32);
      float4 y = *(const float4*)(arow + kc * 32 + 4);
      float av[8] = {x.x, x.y, x.z, x.w, y.x, y.y, y.z, y.w};
      short ah[8], al[8];
#pragma unroll
      for (int j = 0; j < 8; j++) {
        unsigned u = __float_as_uint(av[j]);
        unsigned hb = u >> 16;
        float fh = __uint_as_float(hb << 16);
        ah[j] = (short)hb;
        al[j] = (short)(__float_as_uint(av[j] - fh) >> 16);
      }
      Ahi[kc] = (bf16x8){ah[0], ah[1], ah[2], ah[3], ah[4], ah[5], ah[6], ah[7]};
      Alo[kc] = (bf16x8){al[0], al[1], al[2], al[3], al[4], al[5], al[6], al[7]};
    }
    f32x4 acc0 = {0.f, 0.f, 0.f, 0.f}, acc1 = {0.f, 0.f, 0.f, 0.f};
#pragma unroll
    for (int kc = 0; kc < 4; kc++) {
      int b0 = (((n * 4 + kc) * 2 + 0) * 2) * 512 + l * 8;  // h=0, sp=0
      bf16x8 B0h = *(const bf16x8*)&sTB[b0];
      bf16x8 B0l = *(const bf16x8*)&sTB[b0 + 512];
      int b1 = (((n * 4 + kc) * 2 + 1) * 2) * 512 + l * 8;  // h=1, sp=0
      bf16x8 B1h = *(const bf16x8*)&sTB[b1];
      bf16x8 B1l = *(const bf16x8*)&sTB[b1 + 512];
      acc0 = __builtin_amdgcn_mfma_f32_16x16x32_bf16(Ahi[kc], B0h, acc0, 0, 0, 0);
      acc0 = __builtin_amdgcn_mfma_f32_16x16x32_bf16(Alo[kc], B0h, acc0, 0, 0, 0);
      acc0 = __builtin_amdgcn_mfma_f32_16x16x32_bf16(Ahi[kc], B0l, acc0, 0, 0, 0);
      acc1 = __builtin_amdgcn_mfma_f32_16x16x32_bf16(Ahi[kc], B1h, acc1, 0, 0, 0);
      acc1 = __builtin_amdgcn_mfma_f32_16x16x32_bf16(Alo[kc], B1h, acc1, 0, 0, 0);
      acc1 = __builtin_amdgcn_mfma_f32_16x16x32_bf16(Ahi[kc], B1l, acc1, 0, 0, 0);
    }
    // flush: C row = (l>>4)*4+j, col = l&15 (+16). One atomic per real (e,o).
    int er = (l >> 4) << 2;
    int c = l & 15;
#pragma unroll
    for (int j = 0; j < 4; j++) {
      int idx = idx16 + er + j;
      int d = dstp[idx];
      if (d >= 0) {
        atomicAdd(&agg[(size_t)d * 32 + c], acc0[j] + sTb[n][c]);
        atomicAdd(&agg[(size_t)d * 32 + c + 16], acc1[j] + sTb[n][c + 16]);
      }
    }
  }
}

// ---------------- fused agg-read + GRU: block = 8 nodes x 32 o -------------
__global__ __launch_bounds__(256) void k_agru(
    const float* __restrict__ agg, const float* __restrict__ cbias,
    const float* __restrict__ wih, const float* __restrict__ whh,
    const float* __restrict__ bih, const float* __restrict__ bhh,
    float* __restrict__ hseq, int nV) {
  __shared__ float swT[2][32 * 97];
  __shared__ float sb[2][96], scb[32];
  __shared__ float sx[8][32], shd[8][32];
  int t = threadIdx.x;
  int v0 = blockIdx.x * 8;
  for (int idx = t; idx < 3072; idx += 256) {
    int row = idx >> 5, i = idx & 31;
    swT[0][i * 97 + row] = wih[idx];
    swT[1][i * 97 + row] = whh[idx];
  }
  if (t < 96) { sb[0][t] = bih[t]; sb[1][t] = bhh[t]; }
  if (t < 32) scb[t] = cbias[t];
  {
    int n = t >> 5, v = v0 + n, j = t & 31;
    shd[n][j] = (v < nV) ? hseq[(size_t)v * 32 + j] : 0.f;
    sx[n][j] = (v < nV) ? fmaxf(agg[(size_t)v * 32 + j] + cbias[j], 0.f) : 0.f;
  }
  __syncthreads();
  int n = t >> 5, o = t & 31;
  int v = v0 + n;
  if (v >= nV) return;
  float gir = sb[0][o], giz = sb[0][32 + o], gin = sb[0][64 + o];
  float ghr = sb[1][o], ghz = sb[1][32 + o], ghn = sb[1][64 + o];
#pragma unroll
  for (int i = 0; i < 32; i++) {
    float xi = sx[n][i], hi = shd[n][i];
    gir += xi * swT[0][i * 97 + o];
    giz += xi * swT[0][i * 97 + 32 + o];
    gin += xi * swT[0][i * 97 + 64 + o];
    ghr += hi * swT[1][i * 97 + o];
    ghz += hi * swT[1][i * 97 + 32 + o];
    ghn += hi * swT[1][i * 97 + 64 + o];
  }
  float r = 1.f / (1.f + __expf(-(gir + ghr)));
  float z = 1.f / (1.f + __expf(-(giz + ghz)));
  float ng = tanhf(gin + r * ghn);
  hseq[(size_t)v * 32 + o] = (1.f - z) * ng + z * shd[n][o];
}

// ---------------- decoder: out = relu(h@dw1+db1)@dw2+db2  (V x 64) ---------
__global__ __launch_bounds__(256) void k_dec(
    const float* __restrict__ hseq, const float* __restrict__ w1,
    const float* __restrict__ b1, const float* __restrict__ w2,
    const float* __restrict__ b2, float* __restrict__ out, int nV) {
  __shared__ float sw1[1024], sb1[32], sw2[2048], sb2[64];
  __shared__ float sx[4][32], st1[4][32];
  int t = threadIdx.x;
  int v0 = blockIdx.x * 4;
  for (int i = t; i < 1024; i += 256) sw1[i] = w1[i];
  for (int i = t; i < 2048; i += 256) sw2[i] = w2[i];
  if (t < 32) sb1[t] = b1[t];
  if (t < 64) sb2[t] = b2[t];
  if (t < 128) {
    int g = v0 * 32 + t;
    sx[t >> 5][t & 31] = (g < nV * 32) ? hseq[g] : 0.f;
  }
  __syncthreads();
  if (t < 128) {
    int n = t >> 5, j = t & 31;
    float s = sb1[j];
#pragma unroll
    for (int i = 0; i < 32; i++) s += sx[n][i] * sw1[i * 32 + j];
    st1[n][j] = fmaxf(s, 0.f);
  }
  __syncthreads();
  int n = t >> 6, j = t & 63;
  float s = sb2[j];
#pragma unroll
  for (int i = 0; i < 32; i++) s += st1[n][i] * sw2[i * 64 + j];
  if (v0 + n < nV) out[(size_t)(v0 + n) * 64 + j] = s;
}

extern "C" void kernel_launch(void* const* d_in, const int* in_sizes, int n_in,
                              void* d_out, int out_size, void* d_ws, size_t ws_size,
                              hipStream_t stream) {
  const float* node_feats = (const float*)d_in[0];
  const float* edge_feats = (const float*)d_in[1];
  const int* src = (const int*)d_in[2];
  const int* dst = (const int*)d_in[3];
  const float* proj_w1 = (const float*)d_in[4];
  const float* proj_b1 = (const float*)d_in[5];
  const float* proj_w2 = (const float*)d_in[6];
  const float* proj_b2 = (const float*)d_in[7];
  const float* e_w1 = (const float*)d_in[8];
  const float* e_b1 = (const float*)d_in[9];
  const float* e_w2 = (const float*)d_in[10];
  const float* e_b2 = (const float*)d_in[11];
  const float* conv_bias = (const float*)d_in[12];
  const float* gru_wih = (const float*)d_in[13];
  const float* gru_whh = (const float*)d_in[14];
  const float* gru_bih = (const float*)d_in[15];
  const float* gru_bhh = (const float*)d_in[16];
  const float* dec_w1 = (const float*)d_in[17];
  const float* dec_b1 = (const float*)d_in[18];
  const float* dec_w2 = (const float*)d_in[19];
  const float* dec_b2 = (const float*)d_in[20];
  float* out = (float*)d_out;

  const int nV = in_sizes[0] / 32;
  const int nE = in_sizes[2];
  // worst-case 16-padded idx space
  const int S = (nE + 15 * nV + 255) & ~255;

  // workspace carve-up (~205 MB worst case; proven-safe <= 211)
  char* base = (char*)d_ws;
  size_t off = 0;
  auto carve = [&](size_t bytes) {
    void* r = base + off;
    off = (off + bytes + 255) & ~(size_t)255;
    return r;
  };
  float* aq = (float*)carve((size_t)S * 128 * 4);  // [idx][k] f32
  float* w2t = (float*)carve((size_t)131072 * 4);
  float* hseq = (float*)carve((size_t)nV * 32 * 4);
  float* agg = (float*)carve((size_t)nV * 32 * 4);
  int* countsS = (int*)carve((size_t)nV * 4);
  int* rp16 = (int*)carve((size_t)(nV + 1) * 4);
  int* curS = (int*)carve((size_t)nV * 4);
  int* permS = (int*)carve((size_t)S * 4);
  int* dstp = (int*)carve((size_t)S * 4);
  (void)ws_size;

  const int TB = 256;
  int gE = (nE + TB - 1) / TB;
  int g8 = (nV + 7) / 8;
  int g4 = (nV + 3) / 4;
  int gStep = (nV + NB - 1) / NB;

  // setup
  k_proj<<<g8, TB, 0, stream>>>(node_feats, proj_w1, proj_b1, proj_w2, proj_b2, hseq, nV);
  k_w2t<<<512, TB, 0, stream>>>(e_w2, w2t);
  hipMemsetAsync(countsS, 0, (size_t)nV * 4, stream);
  hipMemsetAsync(dstp, 0xFF, (size_t)S * 4, stream);  // -1 sentinels
  k_count<<<gE, TB, 0, stream>>>(src, countsS, nE);
  k_scan<<<1, 1024, 0, stream>>>(countsS, rp16, nV);
  k_copy<<<(nV + TB - 1) / TB, TB, 0, stream>>>(rp16, curS, nV);
  k_scatter<<<gE, TB, 0, stream>>>(src, dst, curS, permS, dstp, nE);
  k_edgebuild<<<(S + 1) / 2, TB, 0, stream>>>(edge_feats, e_w1, e_b1, permS, dstp,
                                              rp16, aq, nV);

  // 6 message-passing steps
  for (int step = 0; step < 6; step++) {
    hipMemsetAsync(agg, 0, (size_t)nV * 32 * 4, stream);
    k_step<<<gStep, TB, 0, stream>>>(hseq, w2t, e_b2, aq, rp16, dstp, agg, nV);
    k_agru<<<g8, TB, 0, stream>>>(agg, conv_bias, gru_wih, gru_whh,
                                  gru_bih, gru_bhh, hseq, nV);
  }

  // decoder
  k_dec<<<g4, TB, 0, stream>>>(hseq, dec_w1, dec_b1, dec_w2, dec_b2, out, nV);
}

// Round 10
// 2115.091 us; speedup vs baseline: 3.1853x; 3.1853x over previous
//
#include <hip/hip_runtime.h>
#include <hip/hip_bf16.h>

// MPNN GNN: V=12500 (feat 32), E=200000 (feat 16), H=32, 6 steps.
// msg[e,o] = sum_k a[e,k]*T[src[e],k,o] + Tb[src[e],o],  a loop-invariant.
// R10: MFMA edge pass, split-precision 3-GEMM (Ahi@Thi + Alo@Thi + Ahi@Tlo).
// R9 lesson: in-loop f32->bf16 A-split spilled (VGPR 256, 2GB scratch WRITE).
// Fix: A-split precomputed ONCE into bf16 planes aq_hi/aq_lo (loop-invariant);
// edge loop = pure loads + MFMA, ~50 live VGPRs. T computed f32 by VALU per
// block and stored to LDS in B-fragment layout (hi/lo).

#define NB 4  // src nodes per k_step block

typedef __attribute__((ext_vector_type(8))) short bf16x8;
typedef __attribute__((ext_vector_type(4))) float f32x4;
typedef unsigned short ushort_t;

// ---------------- node projection: h = relu(nf@w1+b1)@w2+b2 ----------------
__global__ __launch_bounds__(256) void k_proj(
    const float* __restrict__ nf, const float* __restrict__ w1,
    const float* __restrict__ b1, const float* __restrict__ w2,
    const float* __restrict__ b2, float* __restrict__ hseq, int nV) {
  __shared__ float sw1[1024], sw2[1024], sb1[32], sb2[32];
  __shared__ float sx[8][32], st1[8][32];
  int t = threadIdx.x;
  int v0 = blockIdx.x * 8;
  for (int i = t; i < 1024; i += 256) { sw1[i] = w1[i]; sw2[i] = w2[i]; }
  if (t < 32) { sb1[t] = b1[t]; sb2[t] = b2[t]; }
  {
    int g = v0 * 32 + t;
    sx[t >> 5][t & 31] = (g < nV * 32) ? nf[g] : 0.f;
  }
  __syncthreads();
  int n = t >> 5, j = t & 31;
  float s = sb1[j];
#pragma unroll
  for (int i = 0; i < 32; i++) s += sx[n][i] * sw1[i * 32 + j];
  st1[n][j] = fmaxf(s, 0.f);
  __syncthreads();
  float h = sb2[j];
#pragma unroll
  for (int i = 0; i < 32; i++) h += st1[n][i] * sw2[i * 32 + j];
  if (v0 + n < nV) hseq[(size_t)(v0 + n) * 32 + j] = h;
}

// ---------------- w2 transpose: w2t[(k*32+c)*32+i] = w2[k*1024+i*32+c] -----
__global__ __launch_bounds__(256) void k_w2t(const float* __restrict__ w2,
                                             float* __restrict__ w2t) {
  int id = blockIdx.x * 256 + threadIdx.x;  // 131072 total
  int k = id >> 10, rest = id & 1023, i = rest >> 5, c = rest & 31;
  w2t[((k * 32 + c) << 5) + i] = w2[id];
}

// ---------------- CSR by src, padded to multiples of 16 --------------------
__global__ __launch_bounds__(256) void k_count(const int* __restrict__ key,
                                               int* __restrict__ counts, int nE) {
  int e = blockIdx.x * 256 + threadIdx.x;
  if (e < nE) atomicAdd(&counts[key[e]], 1);
}

__global__ __launch_bounds__(1024) void k_scan(const int* __restrict__ counts,
                                               int* __restrict__ row_ptr, int nV) {
  __shared__ int buf[1024];
  __shared__ int s_off;
  int t = threadIdx.x;
  if (t == 0) s_off = 0;
  __syncthreads();
  for (int base = 0; base < nV; base += 1024) {
    int x = (base + t < nV) ? ((counts[base + t] + 15) & ~15) : 0;  // pad to 16
    buf[t] = x;
    __syncthreads();
    for (int d = 1; d < 1024; d <<= 1) {
      int v2 = (t >= d) ? buf[t - d] : 0;
      __syncthreads();
      buf[t] += v2;
      __syncthreads();
    }
    int incl = buf[t];
    int off = s_off;
    __syncthreads();
    if (base + t < nV) row_ptr[base + t] = off + incl - x;  // exclusive
    if (t == 1023) s_off = off + incl;
    __syncthreads();
  }
  if (t == 0) row_ptr[nV] = s_off;
}

__global__ __launch_bounds__(256) void k_copy(const int* __restrict__ row_ptr,
                                              int* __restrict__ cursor, int nV) {
  int v = blockIdx.x * 256 + threadIdx.x;
  if (v < nV) cursor[v] = row_ptr[v];
}

// scatter: perm[p]=edge id, dstp[p]=dst (dstp pre-memset to -1 for pads)
__global__ __launch_bounds__(256) void k_scatter(const int* __restrict__ key,
                                                 const int* __restrict__ dst,
                                                 int* __restrict__ cursor,
                                                 int* __restrict__ perm,
                                                 int* __restrict__ dstp, int nE) {
  int e = blockIdx.x * 256 + threadIdx.x;
  if (e < nE) {
    int p = atomicAdd(&cursor[key[e]], 1);
    perm[p] = e;
    dstp[p] = dst[e];
  }
}

// ------- edge MLP (permuted order) -> split bf16 planes, pads = 0 ----------
// aq_hi[idx][128], aq_lo[idx][128]: a = hi_f + lo_f, |lo| <= 2^-9 |a|.
__global__ __launch_bounds__(256) void k_edgebuild(
    const float* __restrict__ ef, const float* __restrict__ w1,
    const float* __restrict__ b1, const int* __restrict__ perm,
    const int* __restrict__ dstp, const int* __restrict__ rp16,
    ushort_t* __restrict__ aq_hi, ushort_t* __restrict__ aq_lo, int nV) {
  __shared__ float sw1[16 * 128], sb1[128], sef[2 * 16];
  __shared__ int spad[2];
  int t = threadIdx.x;
  int total = rp16[nV];
  int i0 = blockIdx.x * 2;
  if (i0 >= total) return;
  for (int i = t; i < 2048; i += 256) sw1[i] = w1[i];
  if (t < 128) sb1[t] = b1[t];
  if (t < 32) {
    int ii = i0 + (t >> 4);
    bool pad = (ii >= total) || (dstp[ii] < 0);
    if ((t & 15) == 0) spad[t >> 4] = pad ? 1 : 0;
    sef[t] = pad ? 0.f : ef[(size_t)perm[ii] * 16 + (t & 15)];
  }
  __syncthreads();
  int el = t >> 7, c = t & 127;
  int ii = i0 + el;
  if (ii >= total) return;
  float s = sb1[c];
#pragma unroll
  for (int i = 0; i < 16; i++) s += sef[el * 16 + i] * sw1[i * 128 + c];
  s = spad[el] ? 0.f : fmaxf(s, 0.f);
  unsigned u = __float_as_uint(s);
  unsigned hb = u >> 16;
  float fh = __uint_as_float(hb << 16);
  unsigned lb = __float_as_uint(s - fh) >> 16;
  aq_hi[(size_t)ii * 128 + c] = (ushort_t)hb;
  aq_lo[(size_t)ii * 128 + c] = (ushort_t)lb;
}

// ---------------- per-step: VALU T (split bf16 frag LDS) + MFMA edges ------
// LDS sTB ushort[(((n*4+kc)*2+h)*2+sp)*512 + l*8 + j]  (64 KB)
//   holds T[n][kc*32 + (l>>4)*8 + j][(l&15) + 16*h], sp: 0=hi 1=lo
__global__ __launch_bounds__(256) void k_step(
    const float* __restrict__ hseq, const float* __restrict__ w2t,
    const float* __restrict__ b2, const ushort_t* __restrict__ aq_hi,
    const ushort_t* __restrict__ aq_lo, const int* __restrict__ rp16,
    const int* __restrict__ dstp, float* __restrict__ agg, int nV) {
  __shared__ unsigned short sTB[32768];
  __shared__ float sh[NB][32];
  __shared__ float sTb[NB][32];
  __shared__ int s_rp[NB + 1];
  int t = threadIdx.x;
  int v0 = blockIdx.x * NB;
  if (t <= NB) {
    int v = v0 + t;
    if (v > nV) v = nV;
    s_rp[t] = rp16[v];
  }
  if (t < NB * 32) {
    int n = t >> 5, v = v0 + n;
    sh[n][t & 31] = (v < nV) ? hseq[(size_t)v * 32 + (t & 31)] : 0.f;
  }
  __syncthreads();
  int beg = s_rp[0], end = s_rp[NB];
  if (beg == end) return;  // block-uniform

  if (t < NB * 32) {  // Tb[n][o] = sum_i h[n][i]*e_b2[i*32+o]
    int n = t >> 5, o = t & 31;
    float s = 0.f;
#pragma unroll
    for (int i = 0; i < 32; i++) s += sh[n][i] * b2[i * 32 + o];
    sTb[n][o] = s;
  }

  // ---- T-phase: 2 frag-slots per thread; slot = (kc,h,l) ----
#pragma unroll 1
  for (int s = t; s < 512; s += 256) {
    int kc = s >> 7, h = (s >> 6) & 1, l = s & 63;
    int c = (l & 15) + h * 16;
    int kbase = kc * 32 + ((l >> 4) << 3);
    float acc[NB][8];
#pragma unroll
    for (int n = 0; n < NB; n++)
#pragma unroll
      for (int j = 0; j < 8; j++) acc[n][j] = 0.f;
#pragma unroll 1
    for (int j = 0; j < 8; j++) {
      const float4* wp = (const float4*)(w2t + ((size_t)((kbase + j) * 32 + c) << 5));
#pragma unroll
      for (int iq = 0; iq < 8; iq++) {
        float4 w4 = wp[iq];
        int i0 = iq * 4;
#pragma unroll
        for (int n = 0; n < NB; n++) {
          acc[n][j] += sh[n][i0] * w4.x + sh[n][i0 + 1] * w4.y +
                       sh[n][i0 + 2] * w4.z + sh[n][i0 + 3] * w4.w;
        }
      }
    }
#pragma unroll
    for (int n = 0; n < NB; n++) {
      unsigned int hi[4], lo[4];
#pragma unroll
      for (int jp = 0; jp < 4; jp++) {
        float a0 = acc[n][2 * jp], a1 = acc[n][2 * jp + 1];
        unsigned h0 = __float_as_uint(a0) >> 16, h1 = __float_as_uint(a1) >> 16;
        float f0 = __uint_as_float(h0 << 16), f1 = __uint_as_float(h1 << 16);
        unsigned l0 = __float_as_uint(a0 - f0) >> 16;
        unsigned l1 = __float_as_uint(a1 - f1) >> 16;
        hi[jp] = h0 | (h1 << 16);
        lo[jp] = l0 | (l1 << 16);
      }
      int ub = ((((n * 4 + kc) * 2 + h) * 2 + 0) * 64 + l) * 8;
      *(uint4*)&sTB[ub] = make_uint4(hi[0], hi[1], hi[2], hi[3]);
      *(uint4*)&sTB[ub + 512] = make_uint4(lo[0], lo[1], lo[2], lo[3]);
    }
  }
  __syncthreads();

  // ---- edge MFMA phase: wave per 16-edge tile ----
  int wid = t >> 6, l = t & 63;
  int r = l & 15;          // A row within tile
  int kg = (l >> 4) << 3;  // k sub-offset (ushorts)
  int n = 0;
#pragma unroll 1
  for (int idx16 = beg + wid * 16; idx16 < end; idx16 += 64) {
    while (idx16 >= s_rp[n + 1]) n++;
    const ushort_t* ah = aq_hi + (size_t)(idx16 + r) * 128 + kg;
    const ushort_t* al = aq_lo + (size_t)(idx16 + r) * 128 + kg;
    f32x4 acc0 = {0.f, 0.f, 0.f, 0.f}, acc1 = {0.f, 0.f, 0.f, 0.f};
#pragma unroll
    for (int kc = 0; kc < 4; kc++) {
      bf16x8 Ah = *(const bf16x8*)(ah + kc * 32);
      bf16x8 Al = *(const bf16x8*)(al + kc * 32);
      int b0 = ((n * 4 + kc) * 4) * 512 + l * 8;  // h=0,sp=0
      bf16x8 B0h = *(const bf16x8*)&sTB[b0];
      bf16x8 B0l = *(const bf16x8*)&sTB[b0 + 512];
      bf16x8 B1h = *(const bf16x8*)&sTB[b0 + 1024];
      bf16x8 B1l = *(const bf16x8*)&sTB[b0 + 1536];
      acc0 = __builtin_amdgcn_mfma_f32_16x16x32_bf16(Ah, B0h, acc0, 0, 0, 0);
      acc0 = __builtin_amdgcn_mfma_f32_16x16x32_bf16(Al, B0h, acc0, 0, 0, 0);
      acc0 = __builtin_amdgcn_mfma_f32_16x16x32_bf16(Ah, B0l, acc0, 0, 0, 0);
      acc1 = __builtin_amdgcn_mfma_f32_16x16x32_bf16(Ah, B1h, acc1, 0, 0, 0);
      acc1 = __builtin_amdgcn_mfma_f32_16x16x32_bf16(Al, B1h, acc1, 0, 0, 0);
      acc1 = __builtin_amdgcn_mfma_f32_16x16x32_bf16(Ah, B1l, acc1, 0, 0, 0);
    }
    // flush: C row = (l>>4)*4+j, col = l&15 (+16). One atomic per real (e,o).
    int er = (l >> 4) << 2;
    int c = l & 15;
#pragma unroll
    for (int j = 0; j < 4; j++) {
      int idx = idx16 + er + j;
      int d = dstp[idx];
      if (d >= 0) {
        atomicAdd(&agg[(size_t)d * 32 + c], acc0[j] + sTb[n][c]);
        atomicAdd(&agg[(size_t)d * 32 + c + 16], acc1[j] + sTb[n][c + 16]);
      }
    }
  }
}

// ---------------- fused agg-read + GRU: block = 8 nodes x 32 o -------------
__global__ __launch_bounds__(256) void k_agru(
    const float* __restrict__ agg, const float* __restrict__ cbias,
    const float* __restrict__ wih, const float* __restrict__ whh,
    const float* __restrict__ bih, const float* __restrict__ bhh,
    float* __restrict__ hseq, int nV) {
  __shared__ float swT[2][32 * 97];
  __shared__ float sb[2][96], scb[32];
  __shared__ float sx[8][32], shd[8][32];
  int t = threadIdx.x;
  int v0 = blockIdx.x * 8;
  for (int idx = t; idx < 3072; idx += 256) {
    int row = idx >> 5, i = idx & 31;
    swT[0][i * 97 + row] = wih[idx];
    swT[1][i * 97 + row] = whh[idx];
  }
  if (t < 96) { sb[0][t] = bih[t]; sb[1][t] = bhh[t]; }
  if (t < 32) scb[t] = cbias[t];
  {
    int n = t >> 5, v = v0 + n, j = t & 31;
    shd[n][j] = (v < nV) ? hseq[(size_t)v * 32 + j] : 0.f;
    sx[n][j] = (v < nV) ? fmaxf(agg[(size_t)v * 32 + j] + cbias[j], 0.f) : 0.f;
  }
  __syncthreads();
  int n = t >> 5, o = t & 31;
  int v = v0 + n;
  if (v >= nV) return;
  float gir = sb[0][o], giz = sb[0][32 + o], gin = sb[0][64 + o];
  float ghr = sb[1][o], ghz = sb[1][32 + o], ghn = sb[1][64 + o];
#pragma unroll
  for (int i = 0; i < 32; i++) {
    float xi = sx[n][i], hi = shd[n][i];
    gir += xi * swT[0][i * 97 + o];
    giz += xi * swT[0][i * 97 + 32 + o];
    gin += xi * swT[0][i * 97 + 64 + o];
    ghr += hi * swT[1][i * 97 + o];
    ghz += hi * swT[1][i * 97 + 32 + o];
    ghn += hi * swT[1][i * 97 + 64 + o];
  }
  float r = 1.f / (1.f + __expf(-(gir + ghr)));
  float z = 1.f / (1.f + __expf(-(giz + ghz)));
  float ng = tanhf(gin + r * ghn);
  hseq[(size_t)v * 32 + o] = (1.f - z) * ng + z * shd[n][o];
}

// ---------------- decoder: out = relu(h@dw1+db1)@dw2+db2  (V x 64) ---------
__global__ __launch_bounds__(256) void k_dec(
    const float* __restrict__ hseq, const float* __restrict__ w1,
    const float* __restrict__ b1, const float* __restrict__ w2,
    const float* __restrict__ b2, float* __restrict__ out, int nV) {
  __shared__ float sw1[1024], sb1[32], sw2[2048], sb2[64];
  __shared__ float sx[4][32], st1[4][32];
  int t = threadIdx.x;
  int v0 = blockIdx.x * 4;
  for (int i = t; i < 1024; i += 256) sw1[i] = w1[i];
  for (int i = t; i < 2048; i += 256) sw2[i] = w2[i];
  if (t < 32) sb1[t] = b1[t];
  if (t < 64) sb2[t] = b2[t];
  if (t < 128) {
    int g = v0 * 32 + t;
    sx[t >> 5][t & 31] = (g < nV * 32) ? hseq[g] : 0.f;
  }
  __syncthreads();
  if (t < 128) {
    int n = t >> 5, j = t & 31;
    float s = sb1[j];
#pragma unroll
    for (int i = 0; i < 32; i++) s += sx[n][i] * sw1[i * 32 + j];
    st1[n][j] = fmaxf(s, 0.f);
  }
  __syncthreads();
  int n = t >> 6, j = t & 63;
  float s = sb2[j];
#pragma unroll
  for (int i = 0; i < 32; i++) s += st1[n][i] * sw2[i * 64 + j];
  if (v0 + n < nV) out[(size_t)(v0 + n) * 64 + j] = s;
}

extern "C" void kernel_launch(void* const* d_in, const int* in_sizes, int n_in,
                              void* d_out, int out_size, void* d_ws, size_t ws_size,
                              hipStream_t stream) {
  const float* node_feats = (const float*)d_in[0];
  const float* edge_feats = (const float*)d_in[1];
  const int* src = (const int*)d_in[2];
  const int* dst = (const int*)d_in[3];
  const float* proj_w1 = (const float*)d_in[4];
  const float* proj_b1 = (const float*)d_in[5];
  const float* proj_w2 = (const float*)d_in[6];
  const float* proj_b2 = (const float*)d_in[7];
  const float* e_w1 = (const float*)d_in[8];
  const float* e_b1 = (const float*)d_in[9];
  const float* e_w2 = (const float*)d_in[10];
  const float* e_b2 = (const float*)d_in[11];
  const float* conv_bias = (const float*)d_in[12];
  const float* gru_wih = (const float*)d_in[13];
  const float* gru_whh = (const float*)d_in[14];
  const float* gru_bih = (const float*)d_in[15];
  const float* gru_bhh = (const float*)d_in[16];
  const float* dec_w1 = (const float*)d_in[17];
  const float* dec_b1 = (const float*)d_in[18];
  const float* dec_w2 = (const float*)d_in[19];
  const float* dec_b2 = (const float*)d_in[20];
  float* out = (float*)d_out;

  const int nV = in_sizes[0] / 32;
  const int nE = in_sizes[2];
  // worst-case 16-padded idx space
  const int S = (nE + 15 * nV + 255) & ~255;

  // workspace carve-up (~194 MB worst case; proven-safe <= ~205)
  char* base = (char*)d_ws;
  size_t off = 0;
  auto carve = [&](size_t bytes) {
    void* r = base + off;
    off = (off + bytes + 255) & ~(size_t)255;
    return r;
  };
  ushort_t* aq_hi = (ushort_t*)carve((size_t)S * 128 * 2);
  ushort_t* aq_lo = (ushort_t*)carve((size_t)S * 128 * 2);
  float* w2t = (float*)carve((size_t)131072 * 4);
  float* hseq = (float*)carve((size_t)nV * 32 * 4);
  float* agg = (float*)carve((size_t)nV * 32 * 4);
  int* countsS = (int*)carve((size_t)nV * 4);
  int* rp16 = (int*)carve((size_t)(nV + 1) * 4);
  int* curS = (int*)carve((size_t)nV * 4);
  int* permS = (int*)carve((size_t)S * 4);
  int* dstp = (int*)carve((size_t)S * 4);
  (void)ws_size;

  const int TB = 256;
  int gE = (nE + TB - 1) / TB;
  int g8 = (nV + 7) / 8;
  int g4 = (nV + 3) / 4;
  int gStep = (nV + NB - 1) / NB;

  // setup
  k_proj<<<g8, TB, 0, stream>>>(node_feats, proj_w1, proj_b1, proj_w2, proj_b2, hseq, nV);
  k_w2t<<<512, TB, 0, stream>>>(e_w2, w2t);
  hipMemsetAsync(countsS, 0, (size_t)nV * 4, stream);
  hipMemsetAsync(dstp, 0xFF, (size_t)S * 4, stream);  // -1 sentinels
  k_count<<<gE, TB, 0, stream>>>(src, countsS, nE);
  k_scan<<<1, 1024, 0, stream>>>(countsS, rp16, nV);
  k_copy<<<(nV + TB - 1) / TB, TB, 0, stream>>>(rp16, curS, nV);
  k_scatter<<<gE, TB, 0, stream>>>(src, dst, curS, permS, dstp, nE);
  k_edgebuild<<<(S + 1) / 2, TB, 0, stream>>>(edge_feats, e_w1, e_b1, permS, dstp,
                                              rp16, aq_hi, aq_lo, nV);

  // 6 message-passing steps
  for (int step = 0; step < 6; step++) {
    hipMemsetAsync(agg, 0, (size_t)nV * 32 * 4, stream);
    k_step<<<gStep, TB, 0, stream>>>(hseq, w2t, e_b2, aq_hi, aq_lo, rp16, dstp,
                                     agg, nV);
    k_agru<<<g8, TB, 0, stream>>>(agg, conv_bias, gru_wih, gru_whh,
                                  gru_bih, gru_bhh, hseq, nV);
  }

  // decoder
  k_dec<<<g4, TB, 0, stream>>>(hseq, dec_w1, dec_b1, dec_w2, dec_b2, out, nV);
}

// Round 11
// 1176.183 us; speedup vs baseline: 5.7280x; 1.7983x over previous
//
#include <hip/hip_runtime.h>
#include <hip/hip_bf16.h>

// MPNN GNN: V=12500 (feat 32), E=200000 (feat 16), H=32, 6 steps.
// msg[e,o] = sum_k a[e,k]*T[src[e],k,o] + Tb[src[e],o],  a loop-invariant.
// R11: MFMA edge pass (split bf16 3-GEMM, proven R10, absmax 0.0156).
// R10 lesson: T-phase read w2t with lane-stride 128B -> 64 lines per load,
// 77% stall, 313us/step. Fix: original w2 [k][i][c] layout, loop i outer:
// per (j,i) load is ONE 64B line (lanes share c-range, 4-way broadcast).

#define NB 4  // src nodes per k_step block

typedef __attribute__((ext_vector_type(8))) short bf16x8;
typedef __attribute__((ext_vector_type(4))) float f32x4;
typedef unsigned short ushort_t;

// ---------------- node projection: h = relu(nf@w1+b1)@w2+b2 ----------------
__global__ __launch_bounds__(256) void k_proj(
    const float* __restrict__ nf, const float* __restrict__ w1,
    const float* __restrict__ b1, const float* __restrict__ w2,
    const float* __restrict__ b2, float* __restrict__ hseq, int nV) {
  __shared__ float sw1[1024], sw2[1024], sb1[32], sb2[32];
  __shared__ float sx[8][32], st1[8][32];
  int t = threadIdx.x;
  int v0 = blockIdx.x * 8;
  for (int i = t; i < 1024; i += 256) { sw1[i] = w1[i]; sw2[i] = w2[i]; }
  if (t < 32) { sb1[t] = b1[t]; sb2[t] = b2[t]; }
  {
    int g = v0 * 32 + t;
    sx[t >> 5][t & 31] = (g < nV * 32) ? nf[g] : 0.f;
  }
  __syncthreads();
  int n = t >> 5, j = t & 31;
  float s = sb1[j];
#pragma unroll
  for (int i = 0; i < 32; i++) s += sx[n][i] * sw1[i * 32 + j];
  st1[n][j] = fmaxf(s, 0.f);
  __syncthreads();
  float h = sb2[j];
#pragma unroll
  for (int i = 0; i < 32; i++) h += st1[n][i] * sw2[i * 32 + j];
  if (v0 + n < nV) hseq[(size_t)(v0 + n) * 32 + j] = h;
}

// ---------------- CSR by src, padded to multiples of 16 --------------------
__global__ __launch_bounds__(256) void k_count(const int* __restrict__ key,
                                               int* __restrict__ counts, int nE) {
  int e = blockIdx.x * 256 + threadIdx.x;
  if (e < nE) atomicAdd(&counts[key[e]], 1);
}

__global__ __launch_bounds__(1024) void k_scan(const int* __restrict__ counts,
                                               int* __restrict__ row_ptr, int nV) {
  __shared__ int buf[1024];
  __shared__ int s_off;
  int t = threadIdx.x;
  if (t == 0) s_off = 0;
  __syncthreads();
  for (int base = 0; base < nV; base += 1024) {
    int x = (base + t < nV) ? ((counts[base + t] + 15) & ~15) : 0;  // pad to 16
    buf[t] = x;
    __syncthreads();
    for (int d = 1; d < 1024; d <<= 1) {
      int v2 = (t >= d) ? buf[t - d] : 0;
      __syncthreads();
      buf[t] += v2;
      __syncthreads();
    }
    int incl = buf[t];
    int off = s_off;
    __syncthreads();
    if (base + t < nV) row_ptr[base + t] = off + incl - x;  // exclusive
    if (t == 1023) s_off = off + incl;
    __syncthreads();
  }
  if (t == 0) row_ptr[nV] = s_off;
}

__global__ __launch_bounds__(256) void k_copy(const int* __restrict__ row_ptr,
                                              int* __restrict__ cursor, int nV) {
  int v = blockIdx.x * 256 + threadIdx.x;
  if (v < nV) cursor[v] = row_ptr[v];
}

// scatter: perm[p]=edge id, dstp[p]=dst (dstp pre-memset to -1 for pads)
__global__ __launch_bounds__(256) void k_scatter(const int* __restrict__ key,
                                                 const int* __restrict__ dst,
                                                 int* __restrict__ cursor,
                                                 int* __restrict__ perm,
                                                 int* __restrict__ dstp, int nE) {
  int e = blockIdx.x * 256 + threadIdx.x;
  if (e < nE) {
    int p = atomicAdd(&cursor[key[e]], 1);
    perm[p] = e;
    dstp[p] = dst[e];
  }
}

// ------- edge MLP (permuted order) -> split bf16 planes, pads = 0 ----------
__global__ __launch_bounds__(256) void k_edgebuild(
    const float* __restrict__ ef, const float* __restrict__ w1,
    const float* __restrict__ b1, const int* __restrict__ perm,
    const int* __restrict__ dstp, const int* __restrict__ rp16,
    ushort_t* __restrict__ aq_hi, ushort_t* __restrict__ aq_lo, int nV) {
  __shared__ float sw1[16 * 128], sb1[128], sef[2 * 16];
  __shared__ int spad[2];
  int t = threadIdx.x;
  int total = rp16[nV];
  int i0 = blockIdx.x * 2;
  if (i0 >= total) return;
  for (int i = t; i < 2048; i += 256) sw1[i] = w1[i];
  if (t < 128) sb1[t] = b1[t];
  if (t < 32) {
    int ii = i0 + (t >> 4);
    bool pad = (ii >= total) || (dstp[ii] < 0);
    if ((t & 15) == 0) spad[t >> 4] = pad ? 1 : 0;
    sef[t] = pad ? 0.f : ef[(size_t)perm[ii] * 16 + (t & 15)];
  }
  __syncthreads();
  int el = t >> 7, c = t & 127;
  int ii = i0 + el;
  if (ii >= total) return;
  float s = sb1[c];
#pragma unroll
  for (int i = 0; i < 16; i++) s += sef[el * 16 + i] * sw1[i * 128 + c];
  s = spad[el] ? 0.f : fmaxf(s, 0.f);
  unsigned u = __float_as_uint(s);
  unsigned hb = u >> 16;
  float fh = __uint_as_float(hb << 16);
  unsigned lb = __float_as_uint(s - fh) >> 16;
  aq_hi[(size_t)ii * 128 + c] = (ushort_t)hb;
  aq_lo[(size_t)ii * 128 + c] = (ushort_t)lb;
}

// ---------------- per-step: VALU T (split bf16 frag LDS) + MFMA edges ------
// LDS sTB ushort[(((n*4+kc)*2+h)*2+sp)*512 + l*8 + j]  (64 KB)
//   holds T[n][kc*32 + (l>>4)*8 + j][(l&15) + 16*h], sp: 0=hi 1=lo
__global__ __launch_bounds__(256) void k_step(
    const float* __restrict__ hseq, const float* __restrict__ w2,
    const float* __restrict__ b2, const ushort_t* __restrict__ aq_hi,
    const ushort_t* __restrict__ aq_lo, const int* __restrict__ rp16,
    const int* __restrict__ dstp, float* __restrict__ agg, int nV) {
  __shared__ unsigned short sTB[32768];
  __shared__ float sh[NB][32];
  __shared__ float sTb[NB][32];
  __shared__ int s_rp[NB + 1];
  int t = threadIdx.x;
  int v0 = blockIdx.x * NB;
  if (t <= NB) {
    int v = v0 + t;
    if (v > nV) v = nV;
    s_rp[t] = rp16[v];
  }
  if (t < NB * 32) {
    int n = t >> 5, v = v0 + n;
    sh[n][t & 31] = (v < nV) ? hseq[(size_t)v * 32 + (t & 31)] : 0.f;
  }
  __syncthreads();
  int beg = s_rp[0], end = s_rp[NB];
  if (beg == end) return;  // block-uniform

  if (t < NB * 32) {  // Tb[n][o] = sum_i h[n][i]*e_b2[i*32+o]
    int n = t >> 5, o = t & 31;
    float s = 0.f;
#pragma unroll
    for (int i = 0; i < 32; i++) s += sh[n][i] * b2[i * 32 + o];
    sTb[n][o] = s;
  }

  // ---- T-phase: 2 frag-slots per thread; slot = (kc,h,l) ----
  // Loads from ORIGINAL w2 layout [k][i][c]: per (j,i) a wave reads one 64B
  // line (c = (l&15)+16h, 4-way replicated across lane quads). i outer for ILP.
#pragma unroll 1
  for (int s = t; s < 512; s += 256) {
    int kc = s >> 7, h = (s >> 6) & 1, l = s & 63;
    int c = (l & 15) + h * 16;
    int kbase = kc * 32 + ((l >> 4) << 3);
    const float* wb = w2 + (size_t)kbase * 1024 + c;  // + j*1024 + i*32
    float acc[NB][8];
#pragma unroll
    for (int n = 0; n < NB; n++)
#pragma unroll
      for (int j = 0; j < 8; j++) acc[n][j] = 0.f;
#pragma unroll 4
    for (int i = 0; i < 32; i++) {
      float wv[8];
#pragma unroll
      for (int j = 0; j < 8; j++) wv[j] = wb[j * 1024 + i * 32];
      float shv[NB];
#pragma unroll
      for (int n = 0; n < NB; n++) shv[n] = sh[n][i];
#pragma unroll
      for (int n = 0; n < NB; n++)
#pragma unroll
        for (int j = 0; j < 8; j++) acc[n][j] += shv[n] * wv[j];
    }
#pragma unroll
    for (int n = 0; n < NB; n++) {
      unsigned int hi[4], lo[4];
#pragma unroll
      for (int jp = 0; jp < 4; jp++) {
        float a0 = acc[n][2 * jp], a1 = acc[n][2 * jp + 1];
        unsigned h0 = __float_as_uint(a0) >> 16, h1 = __float_as_uint(a1) >> 16;
        float f0 = __uint_as_float(h0 << 16), f1 = __uint_as_float(h1 << 16);
        unsigned l0 = __float_as_uint(a0 - f0) >> 16;
        unsigned l1 = __float_as_uint(a1 - f1) >> 16;
        hi[jp] = h0 | (h1 << 16);
        lo[jp] = l0 | (l1 << 16);
      }
      int ub = ((((n * 4 + kc) * 2 + h) * 2 + 0) * 64 + l) * 8;
      *(uint4*)&sTB[ub] = make_uint4(hi[0], hi[1], hi[2], hi[3]);
      *(uint4*)&sTB[ub + 512] = make_uint4(lo[0], lo[1], lo[2], lo[3]);
    }
  }
  __syncthreads();

  // ---- edge MFMA phase: wave per 16-edge tile ----
  int wid = t >> 6, l = t & 63;
  int r = l & 15;          // A row within tile
  int kg = (l >> 4) << 3;  // k sub-offset (ushorts)
  int n = 0;
#pragma unroll 1
  for (int idx16 = beg + wid * 16; idx16 < end; idx16 += 64) {
    while (idx16 >= s_rp[n + 1]) n++;
    const ushort_t* ah = aq_hi + (size_t)(idx16 + r) * 128 + kg;
    const ushort_t* al = aq_lo + (size_t)(idx16 + r) * 128 + kg;
    f32x4 acc0 = {0.f, 0.f, 0.f, 0.f}, acc1 = {0.f, 0.f, 0.f, 0.f};
#pragma unroll
    for (int kc = 0; kc < 4; kc++) {
      bf16x8 Ah = *(const bf16x8*)(ah + kc * 32);
      bf16x8 Al = *(const bf16x8*)(al + kc * 32);
      int b0 = ((n * 4 + kc) * 4) * 512 + l * 8;  // h=0,sp=0
      bf16x8 B0h = *(const bf16x8*)&sTB[b0];
      bf16x8 B0l = *(const bf16x8*)&sTB[b0 + 512];
      bf16x8 B1h = *(const bf16x8*)&sTB[b0 + 1024];
      bf16x8 B1l = *(const bf16x8*)&sTB[b0 + 1536];
      acc0 = __builtin_amdgcn_mfma_f32_16x16x32_bf16(Ah, B0h, acc0, 0, 0, 0);
      acc0 = __builtin_amdgcn_mfma_f32_16x16x32_bf16(Al, B0h, acc0, 0, 0, 0);
      acc0 = __builtin_amdgcn_mfma_f32_16x16x32_bf16(Ah, B0l, acc0, 0, 0, 0);
      acc1 = __builtin_amdgcn_mfma_f32_16x16x32_bf16(Ah, B1h, acc1, 0, 0, 0);
      acc1 = __builtin_amdgcn_mfma_f32_16x16x32_bf16(Al, B1h, acc1, 0, 0, 0);
      acc1 = __builtin_amdgcn_mfma_f32_16x16x32_bf16(Ah, B1l, acc1, 0, 0, 0);
    }
    // flush: C row = (l>>4)*4+j, col = l&15 (+16). One atomic per real (e,o).
    int er = (l >> 4) << 2;
    int c = l & 15;
#pragma unroll
    for (int j = 0; j < 4; j++) {
      int idx = idx16 + er + j;
      int d = dstp[idx];
      if (d >= 0) {
        atomicAdd(&agg[(size_t)d * 32 + c], acc0[j] + sTb[n][c]);
        atomicAdd(&agg[(size_t)d * 32 + c + 16], acc1[j] + sTb[n][c + 16]);
      }
    }
  }
}

// ---------------- fused agg-read + GRU: block = 8 nodes x 32 o -------------
__global__ __launch_bounds__(256) void k_agru(
    const float* __restrict__ agg, const float* __restrict__ cbias,
    const float* __restrict__ wih, const float* __restrict__ whh,
    const float* __restrict__ bih, const float* __restrict__ bhh,
    float* __restrict__ hseq, int nV) {
  __shared__ float swT[2][32 * 97];
  __shared__ float sb[2][96], scb[32];
  __shared__ float sx[8][32], shd[8][32];
  int t = threadIdx.x;
  int v0 = blockIdx.x * 8;
  for (int idx = t; idx < 3072; idx += 256) {
    int row = idx >> 5, i = idx & 31;
    swT[0][i * 97 + row] = wih[idx];
    swT[1][i * 97 + row] = whh[idx];
  }
  if (t < 96) { sb[0][t] = bih[t]; sb[1][t] = bhh[t]; }
  if (t < 32) scb[t] = cbias[t];
  {
    int n = t >> 5, v = v0 + n, j = t & 31;
    shd[n][j] = (v < nV) ? hseq[(size_t)v * 32 + j] : 0.f;
    sx[n][j] = (v < nV) ? fmaxf(agg[(size_t)v * 32 + j] + cbias[j], 0.f) : 0.f;
  }
  __syncthreads();
  int n = t >> 5, o = t & 31;
  int v = v0 + n;
  if (v >= nV) return;
  float gir = sb[0][o], giz = sb[0][32 + o], gin = sb[0][64 + o];
  float ghr = sb[1][o], ghz = sb[1][32 + o], ghn = sb[1][64 + o];
#pragma unroll
  for (int i = 0; i < 32; i++) {
    float xi = sx[n][i], hi = shd[n][i];
    gir += xi * swT[0][i * 97 + o];
    giz += xi * swT[0][i * 97 + 32 + o];
    gin += xi * swT[0][i * 97 + 64 + o];
    ghr += hi * swT[1][i * 97 + o];
    ghz += hi * swT[1][i * 97 + 32 + o];
    ghn += hi * swT[1][i * 97 + 64 + o];
  }
  float r = 1.f / (1.f + __expf(-(gir + ghr)));
  float z = 1.f / (1.f + __expf(-(giz + ghz)));
  float ng = tanhf(gin + r * ghn);
  hseq[(size_t)v * 32 + o] = (1.f - z) * ng + z * shd[n][o];
}

// ---------------- decoder: out = relu(h@dw1+db1)@dw2+db2  (V x 64) ---------
__global__ __launch_bounds__(256) void k_dec(
    const float* __restrict__ hseq, const float* __restrict__ w1,
    const float* __restrict__ b1, const float* __restrict__ w2,
    const float* __restrict__ b2, float* __restrict__ out, int nV) {
  __shared__ float sw1[1024], sb1[32], sw2[2048], sb2[64];
  __shared__ float sx[4][32], st1[4][32];
  int t = threadIdx.x;
  int v0 = blockIdx.x * 4;
  for (int i = t; i < 1024; i += 256) sw1[i] = w1[i];
  for (int i = t; i < 2048; i += 256) sw2[i] = w2[i];
  if (t < 32) sb1[t] = b1[t];
  if (t < 64) sb2[t] = b2[t];
  if (t < 128) {
    int g = v0 * 32 + t;
    sx[t >> 5][t & 31] = (g < nV * 32) ? hseq[g] : 0.f;
  }
  __syncthreads();
  if (t < 128) {
    int n = t >> 5, j = t & 31;
    float s = sb1[j];
#pragma unroll
    for (int i = 0; i < 32; i++) s += sx[n][i] * sw1[i * 32 + j];
    st1[n][j] = fmaxf(s, 0.f);
  }
  __syncthreads();
  int n = t >> 6, j = t & 63;
  float s = sb2[j];
#pragma unroll
  for (int i = 0; i < 32; i++) s += st1[n][i] * sw2[i * 64 + j];
  if (v0 + n < nV) out[(size_t)(v0 + n) * 64 + j] = s;
}

extern "C" void kernel_launch(void* const* d_in, const int* in_sizes, int n_in,
                              void* d_out, int out_size, void* d_ws, size_t ws_size,
                              hipStream_t stream) {
  const float* node_feats = (const float*)d_in[0];
  const float* edge_feats = (const float*)d_in[1];
  const int* src = (const int*)d_in[2];
  const int* dst = (const int*)d_in[3];
  const float* proj_w1 = (const float*)d_in[4];
  const float* proj_b1 = (const float*)d_in[5];
  const float* proj_w2 = (const float*)d_in[6];
  const float* proj_b2 = (const float*)d_in[7];
  const float* e_w1 = (const float*)d_in[8];
  const float* e_b1 = (const float*)d_in[9];
  const float* e_w2 = (const float*)d_in[10];
  const float* e_b2 = (const float*)d_in[11];
  const float* conv_bias = (const float*)d_in[12];
  const float* gru_wih = (const float*)d_in[13];
  const float* gru_whh = (const float*)d_in[14];
  const float* gru_bih = (const float*)d_in[15];
  const float* gru_bhh = (const float*)d_in[16];
  const float* dec_w1 = (const float*)d_in[17];
  const float* dec_b1 = (const float*)d_in[18];
  const float* dec_w2 = (const float*)d_in[19];
  const float* dec_b2 = (const float*)d_in[20];
  float* out = (float*)d_out;

  const int nV = in_sizes[0] / 32;
  const int nE = in_sizes[2];
  // worst-case 16-padded idx space
  const int S = (nE + 15 * nV + 255) & ~255;

  // workspace carve-up (~194 MB worst case; proven-safe ~208)
  char* base = (char*)d_ws;
  size_t off = 0;
  auto carve = [&](size_t bytes) {
    void* r = base + off;
    off = (off + bytes + 255) & ~(size_t)255;
    return r;
  };
  ushort_t* aq_hi = (ushort_t*)carve((size_t)S * 128 * 2);
  ushort_t* aq_lo = (ushort_t*)carve((size_t)S * 128 * 2);
  float* hseq = (float*)carve((size_t)nV * 32 * 4);
  float* agg = (float*)carve((size_t)nV * 32 * 4);
  int* countsS = (int*)carve((size_t)nV * 4);
  int* rp16 = (int*)carve((size_t)(nV + 1) * 4);
  int* curS = (int*)carve((size_t)nV * 4);
  int* permS = (int*)carve((size_t)S * 4);
  int* dstp = (int*)carve((size_t)S * 4);
  (void)ws_size;

  const int TB = 256;
  int gE = (nE + TB - 1) / TB;
  int g8 = (nV + 7) / 8;
  int g4 = (nV + 3) / 4;
  int gStep = (nV + NB - 1) / NB;

  // setup
  k_proj<<<g8, TB, 0, stream>>>(node_feats, proj_w1, proj_b1, proj_w2, proj_b2, hseq, nV);
  hipMemsetAsync(countsS, 0, (size_t)nV * 4, stream);
  hipMemsetAsync(dstp, 0xFF, (size_t)S * 4, stream);  // -1 sentinels
  k_count<<<gE, TB, 0, stream>>>(src, countsS, nE);
  k_scan<<<1, 1024, 0, stream>>>(countsS, rp16, nV);
  k_copy<<<(nV + TB - 1) / TB, TB, 0, stream>>>(rp16, curS, nV);
  k_scatter<<<gE, TB, 0, stream>>>(src, dst, curS, permS, dstp, nE);
  k_edgebuild<<<(S + 1) / 2, TB, 0, stream>>>(edge_feats, e_w1, e_b1, permS, dstp,
                                              rp16, aq_hi, aq_lo, nV);

  // 6 message-passing steps
  for (int step = 0; step < 6; step++) {
    hipMemsetAsync(agg, 0, (size_t)nV * 32 * 4, stream);
    k_step<<<gStep, TB, 0, stream>>>(hseq, e_w2, e_b2, aq_hi, aq_lo, rp16, dstp,
                                     agg, nV);
    k_agru<<<g8, TB, 0, stream>>>(agg, conv_bias, gru_wih, gru_whh,
                                  gru_bih, gru_bhh, hseq, nV);
  }

  // decoder
  k_dec<<<g4, TB, 0, stream>>>(hseq, dec_w1, dec_b1, dec_w2, dec_b2, out, nV);
}

// Round 12
// 938.214 us; speedup vs baseline: 7.1809x; 1.2536x over previous
//
#include <hip/hip_runtime.h>
#include <hip/hip_bf16.h>

// MPNN GNN: V=12500 (feat 32), E=200000 (feat 16), H=32, 6 steps.
// msg[e,o] = sum_k a[e,k]*T[src[e],k,o] + Tb[src[e],o],  a loop-invariant.
// R12: (1) dense k_edgebuild (64 real edges/block, pose[] scatter; pads left
// unwritten -- their MFMA C-rows are discarded at flush, row-local). (2) k_step
// NB=8 @ 512 threads, 133 KB LDS (gfx950 cap 160 KB): halves e_w2 L2 traffic.
// Proven: split-bf16 3-GEMM MFMA edge pass (absmax 0.0156), coalesced w2
// T-phase (R11), one atomic per real (e,o).

#define NB 8  // src nodes per k_step block

typedef __attribute__((ext_vector_type(8))) short bf16x8;
typedef __attribute__((ext_vector_type(4))) float f32x4;
typedef unsigned short ushort_t;

// ---------------- node projection: h = relu(nf@w1+b1)@w2+b2 ----------------
__global__ __launch_bounds__(256) void k_proj(
    const float* __restrict__ nf, const float* __restrict__ w1,
    const float* __restrict__ b1, const float* __restrict__ w2,
    const float* __restrict__ b2, float* __restrict__ hseq, int nV) {
  __shared__ float sw1[1024], sw2[1024], sb1[32], sb2[32];
  __shared__ float sx[8][32], st1[8][32];
  int t = threadIdx.x;
  int v0 = blockIdx.x * 8;
  for (int i = t; i < 1024; i += 256) { sw1[i] = w1[i]; sw2[i] = w2[i]; }
  if (t < 32) { sb1[t] = b1[t]; sb2[t] = b2[t]; }
  {
    int g = v0 * 32 + t;
    sx[t >> 5][t & 31] = (g < nV * 32) ? nf[g] : 0.f;
  }
  __syncthreads();
  int n = t >> 5, j = t & 31;
  float s = sb1[j];
#pragma unroll
  for (int i = 0; i < 32; i++) s += sx[n][i] * sw1[i * 32 + j];
  st1[n][j] = fmaxf(s, 0.f);
  __syncthreads();
  float h = sb2[j];
#pragma unroll
  for (int i = 0; i < 32; i++) h += st1[n][i] * sw2[i * 32 + j];
  if (v0 + n < nV) hseq[(size_t)(v0 + n) * 32 + j] = h;
}

// ---------------- CSR by src, padded to multiples of 16 --------------------
__global__ __launch_bounds__(256) void k_count(const int* __restrict__ key,
                                               int* __restrict__ counts, int nE) {
  int e = blockIdx.x * 256 + threadIdx.x;
  if (e < nE) atomicAdd(&counts[key[e]], 1);
}

__global__ __launch_bounds__(1024) void k_scan(const int* __restrict__ counts,
                                               int* __restrict__ row_ptr, int nV) {
  __shared__ int buf[1024];
  __shared__ int s_off;
  int t = threadIdx.x;
  if (t == 0) s_off = 0;
  __syncthreads();
  for (int base = 0; base < nV; base += 1024) {
    int x = (base + t < nV) ? ((counts[base + t] + 15) & ~15) : 0;  // pad to 16
    buf[t] = x;
    __syncthreads();
    for (int d = 1; d < 1024; d <<= 1) {
      int v2 = (t >= d) ? buf[t - d] : 0;
      __syncthreads();
      buf[t] += v2;
      __syncthreads();
    }
    int incl = buf[t];
    int off = s_off;
    __syncthreads();
    if (base + t < nV) row_ptr[base + t] = off + incl - x;  // exclusive
    if (t == 1023) s_off = off + incl;
    __syncthreads();
  }
  if (t == 0) row_ptr[nV] = s_off;
}

__global__ __launch_bounds__(256) void k_copy(const int* __restrict__ row_ptr,
                                              int* __restrict__ cursor, int nV) {
  int v = blockIdx.x * 256 + threadIdx.x;
  if (v < nV) cursor[v] = row_ptr[v];
}

// scatter: pose[e]=padded slot of edge e; dstp[slot]=dst (pads stay -1)
__global__ __launch_bounds__(256) void k_scatter(const int* __restrict__ key,
                                                 const int* __restrict__ dst,
                                                 int* __restrict__ cursor,
                                                 int* __restrict__ pose,
                                                 int* __restrict__ dstp, int nE) {
  int e = blockIdx.x * 256 + threadIdx.x;
  if (e < nE) {
    int p = atomicAdd(&cursor[key[e]], 1);
    pose[e] = p;
    dstp[p] = dst[e];
  }
}

// ------- edge MLP, dense over real edges -> split bf16 planes --------------
// Block = 64 real edges; writes row pose[e]. Pad slots never written (their
// MFMA C-rows are discarded at flush; matmul rows are independent).
__global__ __launch_bounds__(256) void k_edgebuild(
    const float* __restrict__ ef, const float* __restrict__ w1,
    const float* __restrict__ b1, const int* __restrict__ pose,
    ushort_t* __restrict__ aq_hi, ushort_t* __restrict__ aq_lo, int nE) {
  __shared__ float sw1[16 * 128], sb1[128];
  __shared__ float sef[64][17];
  __shared__ int spos[64];
  int t = threadIdx.x;
  int e0 = blockIdx.x * 64;
  if (e0 >= nE) return;
  for (int i = t; i < 2048; i += 256) sw1[i] = w1[i];
  if (t < 128) sb1[t] = b1[t];
  for (int i = t; i < 1024; i += 256) {
    int g = e0 * 16 + i;
    sef[i >> 4][i & 15] = (g < nE * 16) ? ef[g] : 0.f;
  }
  if (t < 64) spos[t] = (e0 + t < nE) ? pose[e0 + t] : 0;
  __syncthreads();
  int c = t & 127;
#pragma unroll 1
  for (int it = 0; it < 32; ++it) {
    int el = it * 2 + (t >> 7);
    if (e0 + el < nE) {
      float s = sb1[c];
#pragma unroll
      for (int i = 0; i < 16; i++) s += sef[el][i] * sw1[i * 128 + c];
      s = fmaxf(s, 0.f);
      unsigned u = __float_as_uint(s);
      unsigned hb = u >> 16;
      float fh = __uint_as_float(hb << 16);
      unsigned lb = __float_as_uint(s - fh) >> 16;
      size_t p = (size_t)spos[el] * 128 + c;
      aq_hi[p] = (ushort_t)hb;
      aq_lo[p] = (ushort_t)lb;
    }
  }
}

// ---------------- per-step: VALU T (split bf16 frag LDS) + MFMA edges ------
// 512 threads, NB=8 nodes, LDS sTB = 128 KB (frag layout, hi/lo planes):
//   ushort[(((n*4+kc)*2+h)*2+sp)*512 + l*8 + j]
//   holds T[n][kc*32 + (l>>4)*8 + j][(l&15) + 16*h], sp: 0=hi 1=lo
__global__ __launch_bounds__(512) void k_step(
    const float* __restrict__ hseq, const float* __restrict__ w2,
    const float* __restrict__ b2, const ushort_t* __restrict__ aq_hi,
    const ushort_t* __restrict__ aq_lo, const int* __restrict__ rp16,
    const int* __restrict__ dstp, float* __restrict__ agg, int nV) {
  __shared__ unsigned short sTB[65536];  // 128 KB
  __shared__ float sh[NB][32];
  __shared__ float sTb[NB][32];
  __shared__ int s_rp[NB + 1];
  int t = threadIdx.x;
  int v0 = blockIdx.x * NB;
  if (t <= NB) {
    int v = v0 + t;
    if (v > nV) v = nV;
    s_rp[t] = rp16[v];
  }
  if (t < NB * 32) {
    int n = t >> 5, v = v0 + n;
    sh[n][t & 31] = (v < nV) ? hseq[(size_t)v * 32 + (t & 31)] : 0.f;
  }
  __syncthreads();
  int beg = s_rp[0], end = s_rp[NB];
  if (beg == end) return;  // block-uniform

  if (t < NB * 32) {  // Tb[n][o] = sum_i h[n][i]*e_b2[i*32+o]
    int n = t >> 5, o = t & 31;
    float s = 0.f;
#pragma unroll
    for (int i = 0; i < 32; i++) s += sh[n][i] * b2[i * 32 + o];
    sTb[n][o] = s;
  }

  // ---- T-phase: each thread owns one (kc,h,l) slot for all 8 nodes ----
  // w2 original layout [k][i][c]: per (j,i) a wave reads few 64B lines.
  {
    int kc = t >> 7, h = (t >> 6) & 1, l = t & 63;
    int c = (l & 15) + h * 16;
    int kbase = kc * 32 + ((l >> 4) << 3);
    const float* wb = w2 + (size_t)kbase * 1024 + c;  // + j*1024 + i*32
    float acc[NB][8];
#pragma unroll
    for (int n = 0; n < NB; n++)
#pragma unroll
      for (int j = 0; j < 8; j++) acc[n][j] = 0.f;
#pragma unroll 4
    for (int i = 0; i < 32; i++) {
      float wv[8];
#pragma unroll
      for (int j = 0; j < 8; j++) wv[j] = wb[j * 1024 + i * 32];
      float shv[NB];
#pragma unroll
      for (int n = 0; n < NB; n++) shv[n] = sh[n][i];
#pragma unroll
      for (int n = 0; n < NB; n++)
#pragma unroll
        for (int j = 0; j < 8; j++) acc[n][j] += shv[n] * wv[j];
    }
#pragma unroll
    for (int n = 0; n < NB; n++) {
      unsigned int hi[4], lo[4];
#pragma unroll
      for (int jp = 0; jp < 4; jp++) {
        float a0 = acc[n][2 * jp], a1 = acc[n][2 * jp + 1];
        unsigned h0 = __float_as_uint(a0) >> 16, h1 = __float_as_uint(a1) >> 16;
        float f0 = __uint_as_float(h0 << 16), f1 = __uint_as_float(h1 << 16);
        unsigned l0 = __float_as_uint(a0 - f0) >> 16;
        unsigned l1 = __float_as_uint(a1 - f1) >> 16;
        hi[jp] = h0 | (h1 << 16);
        lo[jp] = l0 | (l1 << 16);
      }
      int ub = ((((n * 4 + kc) * 2 + h) * 2 + 0) * 64 + l) * 8;
      *(uint4*)&sTB[ub] = make_uint4(hi[0], hi[1], hi[2], hi[3]);
      *(uint4*)&sTB[ub + 512] = make_uint4(lo[0], lo[1], lo[2], lo[3]);
    }
  }
  __syncthreads();

  // ---- edge MFMA phase: 8 waves, wave per 16-edge tile ----
  int wid = t >> 6, l = t & 63;
  int r = l & 15;          // A row within tile
  int kg = (l >> 4) << 3;  // k sub-offset (ushorts)
  int n = 0;
#pragma unroll 1
  for (int idx16 = beg + wid * 16; idx16 < end; idx16 += 128) {
    while (idx16 >= s_rp[n + 1]) n++;
    const ushort_t* ah = aq_hi + (size_t)(idx16 + r) * 128 + kg;
    const ushort_t* al = aq_lo + (size_t)(idx16 + r) * 128 + kg;
    f32x4 acc0 = {0.f, 0.f, 0.f, 0.f}, acc1 = {0.f, 0.f, 0.f, 0.f};
#pragma unroll
    for (int kc = 0; kc < 4; kc++) {
      bf16x8 Ah = *(const bf16x8*)(ah + kc * 32);
      bf16x8 Al = *(const bf16x8*)(al + kc * 32);
      int b0 = ((n * 4 + kc) * 4) * 512 + l * 8;  // h=0,sp=0
      bf16x8 B0h = *(const bf16x8*)&sTB[b0];
      bf16x8 B0l = *(const bf16x8*)&sTB[b0 + 512];
      bf16x8 B1h = *(const bf16x8*)&sTB[b0 + 1024];
      bf16x8 B1l = *(const bf16x8*)&sTB[b0 + 1536];
      acc0 = __builtin_amdgcn_mfma_f32_16x16x32_bf16(Ah, B0h, acc0, 0, 0, 0);
      acc0 = __builtin_amdgcn_mfma_f32_16x16x32_bf16(Al, B0h, acc0, 0, 0, 0);
      acc0 = __builtin_amdgcn_mfma_f32_16x16x32_bf16(Ah, B0l, acc0, 0, 0, 0);
      acc1 = __builtin_amdgcn_mfma_f32_16x16x32_bf16(Ah, B1h, acc1, 0, 0, 0);
      acc1 = __builtin_amdgcn_mfma_f32_16x16x32_bf16(Al, B1h, acc1, 0, 0, 0);
      acc1 = __builtin_amdgcn_mfma_f32_16x16x32_bf16(Ah, B1l, acc1, 0, 0, 0);
    }
    // flush: C row = (l>>4)*4+j, col = l&15 (+16). One atomic per real (e,o).
    int er = (l >> 4) << 2;
    int c = l & 15;
#pragma unroll
    for (int j = 0; j < 4; j++) {
      int idx = idx16 + er + j;
      int d = dstp[idx];
      if (d >= 0) {
        atomicAdd(&agg[(size_t)d * 32 + c], acc0[j] + sTb[n][c]);
        atomicAdd(&agg[(size_t)d * 32 + c + 16], acc1[j] + sTb[n][c + 16]);
      }
    }
  }
}

// ---------------- fused agg-read + GRU: block = 8 nodes x 32 o -------------
__global__ __launch_bounds__(256) void k_agru(
    const float* __restrict__ agg, const float* __restrict__ cbias,
    const float* __restrict__ wih, const float* __restrict__ whh,
    const float* __restrict__ bih, const float* __restrict__ bhh,
    float* __restrict__ hseq, int nV) {
  __shared__ float swT[2][32 * 97];
  __shared__ float sb[2][96], scb[32];
  __shared__ float sx[8][32], shd[8][32];
  int t = threadIdx.x;
  int v0 = blockIdx.x * 8;
  for (int idx = t; idx < 3072; idx += 256) {
    int row = idx >> 5, i = idx & 31;
    swT[0][i * 97 + row] = wih[idx];
    swT[1][i * 97 + row] = whh[idx];
  }
  if (t < 96) { sb[0][t] = bih[t]; sb[1][t] = bhh[t]; }
  if (t < 32) scb[t] = cbias[t];
  {
    int n = t >> 5, v = v0 + n, j = t & 31;
    shd[n][j] = (v < nV) ? hseq[(size_t)v * 32 + j] : 0.f;
    sx[n][j] = (v < nV) ? fmaxf(agg[(size_t)v * 32 + j] + cbias[j], 0.f) : 0.f;
  }
  __syncthreads();
  int n = t >> 5, o = t & 31;
  int v = v0 + n;
  if (v >= nV) return;
  float gir = sb[0][o], giz = sb[0][32 + o], gin = sb[0][64 + o];
  float ghr = sb[1][o], ghz = sb[1][32 + o], ghn = sb[1][64 + o];
#pragma unroll
  for (int i = 0; i < 32; i++) {
    float xi = sx[n][i], hi = shd[n][i];
    gir += xi * swT[0][i * 97 + o];
    giz += xi * swT[0][i * 97 + 32 + o];
    gin += xi * swT[0][i * 97 + 64 + o];
    ghr += hi * swT[1][i * 97 + o];
    ghz += hi * swT[1][i * 97 + 32 + o];
    ghn += hi * swT[1][i * 97 + 64 + o];
  }
  float r = 1.f / (1.f + __expf(-(gir + ghr)));
  float z = 1.f / (1.f + __expf(-(giz + ghz)));
  float ng = tanhf(gin + r * ghn);
  hseq[(size_t)v * 32 + o] = (1.f - z) * ng + z * shd[n][o];
}

// ---------------- decoder: out = relu(h@dw1+db1)@dw2+db2  (V x 64) ---------
__global__ __launch_bounds__(256) void k_dec(
    const float* __restrict__ hseq, const float* __restrict__ w1,
    const float* __restrict__ b1, const float* __restrict__ w2,
    const float* __restrict__ b2, float* __restrict__ out, int nV) {
  __shared__ float sw1[1024], sb1[32], sw2[2048], sb2[64];
  __shared__ float sx[4][32], st1[4][32];
  int t = threadIdx.x;
  int v0 = blockIdx.x * 4;
  for (int i = t; i < 1024; i += 256) sw1[i] = w1[i];
  for (int i = t; i < 2048; i += 256) sw2[i] = w2[i];
  if (t < 32) sb1[t] = b1[t];
  if (t < 64) sb2[t] = b2[t];
  if (t < 128) {
    int g = v0 * 32 + t;
    sx[t >> 5][t & 31] = (g < nV * 32) ? hseq[g] : 0.f;
  }
  __syncthreads();
  if (t < 128) {
    int n = t >> 5, j = t & 31;
    float s = sb1[j];
#pragma unroll
    for (int i = 0; i < 32; i++) s += sx[n][i] * sw1[i * 32 + j];
    st1[n][j] = fmaxf(s, 0.f);
  }
  __syncthreads();
  int n = t >> 6, j = t & 63;
  float s = sb2[j];
#pragma unroll
  for (int i = 0; i < 32; i++) s += st1[n][i] * sw2[i * 64 + j];
  if (v0 + n < nV) out[(size_t)(v0 + n) * 64 + j] = s;
}

extern "C" void kernel_launch(void* const* d_in, const int* in_sizes, int n_in,
                              void* d_out, int out_size, void* d_ws, size_t ws_size,
                              hipStream_t stream) {
  const float* node_feats = (const float*)d_in[0];
  const float* edge_feats = (const float*)d_in[1];
  const int* src = (const int*)d_in[2];
  const int* dst = (const int*)d_in[3];
  const float* proj_w1 = (const float*)d_in[4];
  const float* proj_b1 = (const float*)d_in[5];
  const float* proj_w2 = (const float*)d_in[6];
  const float* proj_b2 = (const float*)d_in[7];
  const float* e_w1 = (const float*)d_in[8];
  const float* e_b1 = (const float*)d_in[9];
  const float* e_w2 = (const float*)d_in[10];
  const float* e_b2 = (const float*)d_in[11];
  const float* conv_bias = (const float*)d_in[12];
  const float* gru_wih = (const float*)d_in[13];
  const float* gru_whh = (const float*)d_in[14];
  const float* gru_bih = (const float*)d_in[15];
  const float* gru_bhh = (const float*)d_in[16];
  const float* dec_w1 = (const float*)d_in[17];
  const float* dec_b1 = (const float*)d_in[18];
  const float* dec_w2 = (const float*)d_in[19];
  const float* dec_b2 = (const float*)d_in[20];
  float* out = (float*)d_out;

  const int nV = in_sizes[0] / 32;
  const int nE = in_sizes[2];
  // worst-case 16-padded idx space
  const int S = (nE + 15 * nV + 255) & ~255;

  // workspace carve-up (~206 MB worst case; proven-safe ~208)
  char* base = (char*)d_ws;
  size_t off = 0;
  auto carve = [&](size_t bytes) {
    void* r = base + off;
    off = (off + bytes + 255) & ~(size_t)255;
    return r;
  };
  ushort_t* aq_hi = (ushort_t*)carve((size_t)S * 128 * 2);
  ushort_t* aq_lo = (ushort_t*)carve((size_t)S * 128 * 2);
  float* hseq = (float*)carve((size_t)nV * 32 * 4);
  float* agg = (float*)carve((size_t)nV * 32 * 4);
  int* countsS = (int*)carve((size_t)nV * 4);
  int* rp16 = (int*)carve((size_t)(nV + 1) * 4);
  int* curS = (int*)carve((size_t)nV * 4);
  int* pose = (int*)carve((size_t)nE * 4);
  int* dstp = (int*)carve((size_t)S * 4);
  (void)ws_size;

  const int TB = 256;
  int gE = (nE + TB - 1) / TB;
  int g8 = (nV + 7) / 8;
  int g4 = (nV + 3) / 4;
  int gStep = (nV + NB - 1) / NB;

  // setup
  k_proj<<<g8, TB, 0, stream>>>(node_feats, proj_w1, proj_b1, proj_w2, proj_b2, hseq, nV);
  hipMemsetAsync(countsS, 0, (size_t)nV * 4, stream);
  hipMemsetAsync(dstp, 0xFF, (size_t)S * 4, stream);  // -1 sentinels
  k_count<<<gE, TB, 0, stream>>>(src, countsS, nE);
  k_scan<<<1, 1024, 0, stream>>>(countsS, rp16, nV);
  k_copy<<<(nV + TB - 1) / TB, TB, 0, stream>>>(rp16, curS, nV);
  k_scatter<<<gE, TB, 0, stream>>>(src, dst, curS, pose, dstp, nE);
  k_edgebuild<<<(nE + 63) / 64, TB, 0, stream>>>(edge_feats, e_w1, e_b1, pose,
                                                 aq_hi, aq_lo, nE);

  // 6 message-passing steps
  for (int step = 0; step < 6; step++) {
    hipMemsetAsync(agg, 0, (size_t)nV * 32 * 4, stream);
    k_step<<<gStep, 512, 0, stream>>>(hseq, e_w2, e_b2, aq_hi, aq_lo, rp16, dstp,
                                      agg, nV);
    k_agru<<<g8, TB, 0, stream>>>(agg, conv_bias, gru_wih, gru_whh,
                                  gru_bih, gru_bhh, hseq, nV);
  }

  // decoder
  k_dec<<<g4, TB, 0, stream>>>(hseq, dec_w1, dec_b1, dec_w2, dec_b2, out, nV);
}